// Round 1
// baseline (507.226 us; speedup 1.0000x reference)
//
#include <hip/hip_runtime.h>
#include <hip/hip_bf16.h>

typedef __attribute__((ext_vector_type(8))) short short8;
typedef __attribute__((ext_vector_type(4))) float f32x4;

#define INF_C 1e10f
#define DM 1024
#define SL 2048
#define TL 2048
#define BATCH 8

__device__ __forceinline__ ushort f2bf(float f) {
  union { float f; unsigned u; } c; c.f = f;
  unsigned u = c.u;
  u += 0x7fffu + ((u >> 16) & 1u);
  return (ushort)(u >> 16);
}
__device__ __forceinline__ float bf2f(ushort h) {
  union { unsigned u; float f; } c; c.u = ((unsigned)h) << 16;
  return c.f;
}
__device__ __forceinline__ float wred_sum(float v) {
#pragma unroll
  for (int i = 32; i > 0; i >>= 1) v += __shfl_xor(v, i);
  return v;
}
__device__ __forceinline__ float wred_max(float v) {
#pragma unroll
  for (int i = 32; i > 0; i >>= 1) v = fmaxf(v, __shfl_xor(v, i));
  return v;
}

// ---------------- f32 -> bf16 convert (vectorized) ----------------
__global__ __launch_bounds__(256) void cvt_f32_bf16(const float* __restrict__ in,
                                                    ushort* __restrict__ out, int n4) {
  int i = blockIdx.x * blockDim.x + threadIdx.x;
  int stride = gridDim.x * blockDim.x;
  for (; i < n4; i += stride) {
    float4 v = ((const float4*)in)[i];
    ushort4 o;
    o.x = f2bf(v.x); o.y = f2bf(v.y); o.z = f2bf(v.z); o.w = f2bf(v.w);
    ((ushort4*)out)[i] = o;
  }
}

// ---------------- steps[b] = sum(mask_src)/sum(mask_trg) ----------------
__global__ __launch_bounds__(256) void steps_kernel(const float* __restrict__ ms,
                                                    const float* __restrict__ mt,
                                                    float* __restrict__ steps) {
  int b = blockIdx.x, tid = threadIdx.x;
  float ss = 0.f, ts = 0.f;
  for (int i = tid; i < SL; i += 256) ss += ms[b * SL + i];
  for (int i = tid; i < TL; i += 256) ts += mt[b * TL + i];
  ss = wred_sum(ss); ts = wred_sum(ts);
  __shared__ float s1[4], s2[4];
  int wid = tid >> 6, lane = tid & 63;
  if (lane == 0) { s1[wid] = ss; s2[wid] = ts; }
  __syncthreads();
  if (tid == 0)
    steps[b] = (s1[0] + s1[1] + s1[2] + s1[3]) / (s2[0] + s2[1] + s2[2] + s2[3]);
}

// ------------- per (b,t): l_att row stats, query, gate -------------
// one wave per row; 4 rows per block
__global__ __launch_bounds__(256) void query_kernel(
    const float* __restrict__ key, const float* __restrict__ mask_src,
    const float* __restrict__ gate_w, const float* __restrict__ gate_b,
    const float* __restrict__ steps, ushort* __restrict__ query_bf,
    float* __restrict__ mrow, float* __restrict__ zrow, float* __restrict__ gates) {
  int wid = threadIdx.x >> 6, lane = threadIdx.x & 63;
  int row = blockIdx.x * 4 + wid;
  int b = row >> 11, t = row & (TL - 1);
  float c = steps[b] * (float)t;
  const float* msk = mask_src + b * SL;
  // pass 1: row max of logits
  float lmax = -3e38f;
  for (int s = lane; s < SL; s += 64) {
    float d = (float)s - c;
    float lg = -d * d * (1.f / 0.3f) - INF_C * (1.f - msk[s]);
    lmax = fmaxf(lmax, lg);
  }
  lmax = wred_max(lmax);
  // pass 2: denom
  float zs = 0.f;
  for (int s = lane; s < SL; s += 64) {
    float d = (float)s - c;
    float lg = -d * d * (1.f / 0.3f) - INF_C * (1.f - msk[s]);
    zs += __expf(lg - lmax);
  }
  zs = wred_sum(zs);
  // window accumulate: only s with weight > ~e^-35 contribute
  float R2 = 10.5f - 0.3f * lmax;  // (s-c)^2 <= 0.3*(35 - lmax)
  float R = sqrtf(R2);
  int slo = max(0, (int)floorf(c - R));
  int shi = min(SL - 1, (int)ceilf(c + R));
  f32x4 qv[4];
#pragma unroll
  for (int i = 0; i < 4; i++) qv[i] = (f32x4){0.f, 0.f, 0.f, 0.f};
  const float* kb = key + (long long)b * SL * DM;
  for (int s = slo; s <= shi; ++s) {
    float d = (float)s - c;
    float lg = -d * d * (1.f / 0.3f) - INF_C * (1.f - msk[s]);
    float w = __expf(lg - lmax);
    if (w > 1e-20f) {
      const f32x4* kr = (const f32x4*)(kb + (long long)s * DM);
#pragma unroll
      for (int i = 0; i < 4; i++) qv[i] += w * kr[(i << 6) + lane];
    }
  }
  float invZ = 1.f / zs;
#pragma unroll
  for (int i = 0; i < 4; i++) qv[i] *= invZ;
  // gate = sigmoid(query . gate_w + gate_b)
  const f32x4* gw = (const f32x4*)gate_w;
  float gl = 0.f;
#pragma unroll
  for (int i = 0; i < 4; i++) {
    f32x4 g = gw[(i << 6) + lane];
    gl += qv[i].x * g.x + qv[i].y * g.y + qv[i].z * g.z + qv[i].w * g.w;
  }
  gl = wred_sum(gl);
  float gate = 1.f / (1.f + __expf(-(gl + gate_b[0])));
  // store query as bf16
  ushort* qq = query_bf + (long long)row * DM;
#pragma unroll
  for (int i = 0; i < 4; i++) {
    ushort4 o;
    o.x = f2bf(qv[i].x); o.y = f2bf(qv[i].y); o.z = f2bf(qv[i].z); o.w = f2bf(qv[i].w);
    ((ushort4*)qq)[(i << 6) + lane] = o;
  }
  if (lane == 0) { mrow[row] = lmax; zrow[row] = zs; gates[row] = gate; }
}

// ---------------- bf16 GEMM: C[m,n] = sum_k A[m,k]*B[n,k] (+bias[n]) ----------------
// m97 structure: 128x128 tile, BK=32, 4 waves, global_load_lds width 16
typedef const __attribute__((address_space(1))) void* gp_t;
typedef __attribute__((address_space(3))) void* lp_t;
#define GLDS(g, l) __builtin_amdgcn_global_load_lds((gp_t)(g), (lp_t)(l), 16, 0, 0)

template <bool OUT_BF16, bool HAS_BIAS>
__global__ __launch_bounds__(256) void gemm_bt(
    const ushort* __restrict__ A, const ushort* __restrict__ Bm,
    const float* __restrict__ bias, void* __restrict__ Cout,
    int M, int N, int K, long long sA, long long sB, long long sC) {
  __shared__ ushort As[128 * 32];
  __shared__ ushort Bs[128 * 32];
  int z = blockIdx.z;
  const ushort* Ab = A + (long long)z * sA;
  const ushort* Bb = Bm + (long long)z * sB;
  int tid = threadIdx.x;
  int wid = tid >> 6, lane = tid & 63;
  int wr = wid >> 1, wc = wid & 1;
  int m0 = blockIdx.y * 128, n0 = blockIdx.x * 128;
  int srow = tid >> 2, scol = (tid & 3) * 8;
  const ushort* aSrc = Ab + (long long)(m0 + srow) * K + scol;
  const ushort* bSrc = Bb + (long long)(n0 + srow) * K + scol;
  ushort* AsW = As + (wid << 9);  // wave-uniform LDS base
  ushort* BsW = Bs + (wid << 9);
  const long long r64 = (long long)64 * K;
  f32x4 acc[4][4];
#pragma unroll
  for (int i = 0; i < 4; i++)
#pragma unroll
    for (int j = 0; j < 4; j++) acc[i][j] = (f32x4){0.f, 0.f, 0.f, 0.f};
  int fr = lane & 15, fg = lane >> 4;
  for (int k0 = 0; k0 < K; k0 += 32) {
    GLDS(aSrc, AsW);
    GLDS(aSrc + r64, AsW + 2048);
    GLDS(bSrc, BsW);
    GLDS(bSrc + r64, BsW + 2048);
    aSrc += 32; bSrc += 32;
    __syncthreads();
    short8 af[4], bf[4];
#pragma unroll
    for (int mf = 0; mf < 4; mf++)
      af[mf] = *(const short8*)(As + ((wr * 64 + mf * 16 + fr) * 32 + fg * 8));
#pragma unroll
    for (int nf = 0; nf < 4; nf++)
      bf[nf] = *(const short8*)(Bs + ((wc * 64 + nf * 16 + fr) * 32 + fg * 8));
#pragma unroll
    for (int mf = 0; mf < 4; mf++)
#pragma unroll
      for (int nf = 0; nf < 4; nf++)
        acc[mf][nf] = __builtin_amdgcn_mfma_f32_16x16x32_bf16(af[mf], bf[nf], acc[mf][nf], 0, 0, 0);
    __syncthreads();
  }
  // epilogue: C row=(lane>>4)*4+j, col=lane&15 (verified layout)
#pragma unroll
  for (int mf = 0; mf < 4; mf++) {
#pragma unroll
    for (int nf = 0; nf < 4; nf++) {
      int col = n0 + wc * 64 + nf * 16 + fr;
      int rowb = m0 + wr * 64 + mf * 16 + fg * 4;
      float bv = HAS_BIAS ? bias[col] : 0.f;
#pragma unroll
      for (int j = 0; j < 4; j++) {
        float v = acc[mf][nf][j] + bv;
        long long idx = (long long)z * sC + (long long)(rowb + j) * N + col;
        if (OUT_BF16) ((ushort*)Cout)[idx] = f2bf(v);
        else ((float*)Cout)[idx] = v;
      }
    }
  }
}

// ---------------- final: row softmax of dots + blend with l_att ----------------
__global__ __launch_bounds__(256) void final_kernel(
    const ushort* __restrict__ dots, const float* __restrict__ mask_src,
    const float* __restrict__ steps, const float* __restrict__ mrow,
    const float* __restrict__ zrow, const float* __restrict__ gates,
    float* __restrict__ out) {
  int row = blockIdx.x;
  int b = row >> 11, t = row & (TL - 1);
  int tid = threadIdx.x;
  int wid = tid >> 6, lane = tid & 63;
  const ushort* dr = dots + (long long)row * SL;
  const float* msk = mask_src + b * SL;
  ushort4 u0 = ((const ushort4*)dr)[tid * 2];
  ushort4 u1 = ((const ushort4*)dr)[tid * 2 + 1];
  float4 mk0 = ((const float4*)msk)[tid * 2];
  float4 mk1 = ((const float4*)msk)[tid * 2 + 1];
  float mk[8] = {mk0.x, mk0.y, mk0.z, mk0.w, mk1.x, mk1.y, mk1.z, mk1.w};
  float li[8];
  li[0] = bf2f(u0.x); li[1] = bf2f(u0.y); li[2] = bf2f(u0.z); li[3] = bf2f(u0.w);
  li[4] = bf2f(u1.x); li[5] = bf2f(u1.y); li[6] = bf2f(u1.z); li[7] = bf2f(u1.w);
  float lmax = -3e38f;
#pragma unroll
  for (int j = 0; j < 8; j++) {
    li[j] = (li[j] - (1.f - mk[j]) * INF_C) * (1.f / 32.f);
    lmax = fmaxf(lmax, li[j]);
  }
  __shared__ float sm[4], ss[4];
  lmax = wred_max(lmax);
  if (lane == 0) sm[wid] = lmax;
  __syncthreads();
  float m2 = fmaxf(fmaxf(sm[0], sm[1]), fmaxf(sm[2], sm[3]));
  float p[8], lsum = 0.f;
#pragma unroll
  for (int j = 0; j < 8; j++) { p[j] = __expf(li[j] - m2); lsum += p[j]; }
  lsum = wred_sum(lsum);
  if (lane == 0) ss[wid] = lsum;
  __syncthreads();
  float invZ2 = 1.f / (ss[0] + ss[1] + ss[2] + ss[3]);
  float c = steps[b] * (float)t;
  float m1 = mrow[row];
  float invZ1 = 1.f / zrow[row];
  float g = gates[row], omg = 1.f - g;
  float o[8];
#pragma unroll
  for (int j = 0; j < 8; j++) {
    int s = tid * 8 + j;
    float d = (float)s - c;
    float l1 = -d * d * (1.f / 0.3f) - (1.f - mk[j]) * INF_C;
    float la = __expf(l1 - m1) * invZ1;
    o[j] = omg * p[j] * invZ2 + g * la;
  }
  float4* op = (float4*)(out + (long long)row * SL);
  op[tid * 2] = (float4){o[0], o[1], o[2], o[3]};
  op[tid * 2 + 1] = (float4){o[4], o[5], o[6], o[7]};
}

extern "C" void kernel_launch(void* const* d_in, const int* in_sizes, int n_in,
                              void* d_out, int out_size, void* d_ws, size_t ws_size,
                              hipStream_t stream) {
  const float* key      = (const float*)d_in[0];
  const float* mask_src = (const float*)d_in[1];
  const float* mask_trg = (const float*)d_in[2];
  const float* wq_w     = (const float*)d_in[3];
  const float* wq_b     = (const float*)d_in[4];
  const float* wk_w     = (const float*)d_in[5];
  const float* wk_b     = (const float*)d_in[6];
  const float* gate_w   = (const float*)d_in[7];
  const float* gate_b   = (const float*)d_in[8];
  float* out = (float*)d_out;

  // ws layout (elements)
  const long long nKD = (long long)BATCH * SL * DM;   // 16,777,216
  const long long nWW = (long long)DM * DM;           // 1,048,576
  const long long nTS = (long long)BATCH * TL * SL;   // 33,554,432
  ushort* key_bf   = (ushort*)d_ws;
  ushort* wk_bf    = key_bf + nKD;
  ushort* wq_bf    = wk_bf + nWW;
  ushort* query_bf = wq_bf + nWW;
  ushort* k_bf     = query_bf + nKD;
  ushort* q_bf     = k_bf + nKD;
  ushort* dots     = q_bf + nKD;
  float*  steps    = (float*)(dots + nTS);
  float*  mrow     = steps + 8;
  float*  zrow     = mrow + BATCH * TL;
  float*  gates    = zrow + BATCH * TL;
  size_t needed = (size_t)((char*)(gates + BATCH * TL) - (char*)d_ws);
  if (ws_size < needed) return;  // signals as stub-like absmax if ws too small

  cvt_f32_bf16<<<2048, 256, 0, stream>>>(key, key_bf, (int)(nKD / 4));
  cvt_f32_bf16<<<512, 256, 0, stream>>>(wk_w, wk_bf, (int)(nWW / 4));
  cvt_f32_bf16<<<512, 256, 0, stream>>>(wq_w, wq_bf, (int)(nWW / 4));
  steps_kernel<<<BATCH, 256, 0, stream>>>(mask_src, mask_trg, steps);
  query_kernel<<<BATCH * TL / 4, 256, 0, stream>>>(key, mask_src, gate_w, gate_b,
                                                   steps, query_bf, mrow, zrow, gates);
  // k = key @ wk^T + wk_b   [16384,1024]x[1024,1024]
  gemm_bt<true, true><<<dim3(8, 128, 1), 256, 0, stream>>>(
      key_bf, wk_bf, wk_b, k_bf, BATCH * SL, DM, DM, 0, 0, 0);
  // q = query @ wq^T + wq_b
  gemm_bt<true, true><<<dim3(8, 128, 1), 256, 0, stream>>>(
      query_bf, wq_bf, wq_b, q_bf, BATCH * TL, DM, DM, 0, 0, 0);
  // dots[b] = q[b] @ k[b]^T   [2048,1024]x[2048,1024]^T per batch
  gemm_bt<true, false><<<dim3(16, 16, BATCH), 256, 0, stream>>>(
      q_bf, k_bf, nullptr, dots, TL, SL, DM,
      (long long)TL * DM, (long long)SL * DM, (long long)TL * SL);
  final_kernel<<<BATCH * TL, 256, 0, stream>>>(dots, mask_src, steps, mrow, zrow,
                                               gates, out);
}